// Round 11
// baseline (383.414 us; speedup 1.0000x reference)
//
#include <hip/hip_runtime.h>

// GCN: 2x GraphConv(norm='both') + per-graph mean + [hg|perm] @ Wc + bc
// N=100000, E=1600000, D=H=128, P=64, C=10, G=128
// R11: degree-sorted agg schedule (perm from per-bin counting sort in p4) to
// kill intra-wave degree divergence; agg back to unroll-4 (VGPR 24, occ 71%).

#define NUM_G 128
#define PB_EDGES 4096   // edges per partition block
#define W_BIN 128       // nodes per bin (key>>7)

typedef unsigned int uint32;
typedef short bf16x8 __attribute__((ext_vector_type(8)));
typedef float f32x4 __attribute__((ext_vector_type(4)));

__device__ __forceinline__ float bflo(uint32 u) { return __uint_as_float(u << 16); }
__device__ __forceinline__ float bfhi(uint32 u) { return __uint_as_float(u & 0xffff0000u); }
__device__ __forceinline__ uint32 f2bf_bits(float f) {  // RNE
    uint32 b = __float_as_uint(f);
    return (b + 0x7fffu + ((b >> 16) & 1u)) >> 16;
}
__device__ __forceinline__ uint32 pack2(float a, float b) {
    return f2bf_bits(a) | (f2bf_bits(b) << 16);
}

// ---- P1: per-block LDS histogram of key>>7. pipe0=dst, pipe1=src ----
__global__ __launch_bounds__(256) void p1_hist(const int* __restrict__ src,
                                               const int* __restrict__ dst, int E,
                                               int NBIN, int B, int* __restrict__ bh) {
    __shared__ int hist[1024];
    int b = blockIdx.x;
    int pipe = (b >= B) ? 1 : 0;
    int bb = pipe ? b - B : b;
    const int* key = pipe ? src : dst;
    for (int i = threadIdx.x; i < NBIN; i += 256) hist[i] = 0;
    __syncthreads();
    int base = bb * PB_EDGES;
    for (int c = threadIdx.x; c < PB_EDGES / 4; c += 256) {
        int e = base + c * 4;
        if (e + 3 < E) {
            int4 k4 = *(const int4*)(key + e);
            atomicAdd(&hist[k4.x >> 7], 1);
            atomicAdd(&hist[k4.y >> 7], 1);
            atomicAdd(&hist[k4.z >> 7], 1);
            atomicAdd(&hist[k4.w >> 7], 1);
        } else {
            for (int i = e; i < E && i < e + 4; i++) atomicAdd(&hist[key[i] >> 7], 1);
        }
    }
    __syncthreads();
    int* outp = bh + (size_t)pipe * NBIN * B;
    for (int k = threadIdx.x; k < NBIN; k += 256)
        outp[(size_t)k * B + bb] = hist[k];
}

// ---- P2a: tot[pipe][k] = sum_b bh[pipe][k][b] ----
__global__ __launch_bounds__(256) void p2a_tot(const int* __restrict__ bh, int NBIN, int B,
                                               int* __restrict__ tot) {
    __shared__ int sc[256];
    int k = blockIdx.x % NBIN, pipe = blockIdx.x / NBIN;
    const int* row = bh + (size_t)pipe * NBIN * B + (size_t)k * B;
    int acc = 0;
    for (int b = threadIdx.x; b < B; b += 256) acc += row[b];
    sc[threadIdx.x] = acc;
    __syncthreads();
    for (int o = 128; o > 0; o >>= 1) {
        if (threadIdx.x < o) sc[threadIdx.x] += sc[threadIdx.x + o];
        __syncthreads();
    }
    if (threadIdx.x == 0) tot[pipe * NBIN + k] = sc[0];
}

// ---- P2c: block (pipe,k): base = prefix(tot) inline; write bstart; scan bh over B ----
__global__ __launch_bounds__(512) void p2c_cursor(const int* __restrict__ bh,
                                                  const int* __restrict__ tot,
                                                  int NBIN, int B, int E,
                                                  int* __restrict__ bstart,
                                                  int* __restrict__ curs) {
    __shared__ int sc[512];
    int k = blockIdx.x % NBIN, pipe = blockIdx.x / NBIN;
    int i = threadIdx.x;
    int pacc = 0;
    for (int kk = i; kk < k; kk += 512) pacc += tot[pipe * NBIN + kk];
    sc[i] = pacc;
    __syncthreads();
    for (int o = 256; o > 0; o >>= 1) {
        if (i < o) sc[i] += sc[i + o];
        __syncthreads();
    }
    int base = sc[0];
    __syncthreads();
    if (i == 0) {
        bstart[pipe * (NBIN + 1) + k] = base;
        if (k == 0) bstart[pipe * (NBIN + 1) + NBIN] = E;
    }
    const int* row = bh + (size_t)pipe * NBIN * B + (size_t)k * B;
    int v = (i < B) ? row[i] : 0;
    sc[i] = v;
    __syncthreads();
    for (int o = 1; o < 512; o <<= 1) {
        int t = (i >= o) ? sc[i - o] : 0;
        __syncthreads();
        sc[i] += t;
        __syncthreads();
    }
    if (i < B)
        curs[(size_t)pipe * B * NBIN + (size_t)i * NBIN + k] = base + sc[i] - v;
}

// ---- P3: scatter edges into bin-partitioned buffers (LDS cursors) ----
// pipe0 entry: src | (dst&127)<<17  (src < 2^17; dst low bits for in-bin CSR)
__global__ __launch_bounds__(256) void p3_scatter(const int* __restrict__ src,
                                                  const int* __restrict__ dst, int E,
                                                  int NBIN, int B, const int* __restrict__ curs,
                                                  int* __restrict__ ebuf, int* __restrict__ sbuf) {
    __shared__ int cur[1024];
    int b = blockIdx.x;
    int pipe = (b >= B) ? 1 : 0;
    int bb = pipe ? b - B : b;
    const int* crow = curs + (size_t)pipe * B * NBIN + (size_t)bb * NBIN;
    for (int i = threadIdx.x; i < NBIN; i += 256) cur[i] = crow[i];
    __syncthreads();
    int base = bb * PB_EDGES;
    if (!pipe) {
        for (int c = threadIdx.x; c < PB_EDGES / 4; c += 256) {
            int e = base + c * 4;
            if (e + 3 < E) {
                int4 s4 = *(const int4*)(src + e);
                int4 d4 = *(const int4*)(dst + e);
                int p;
                p = atomicAdd(&cur[d4.x >> 7], 1); ebuf[p] = s4.x | ((d4.x & 127) << 17);
                p = atomicAdd(&cur[d4.y >> 7], 1); ebuf[p] = s4.y | ((d4.y & 127) << 17);
                p = atomicAdd(&cur[d4.z >> 7], 1); ebuf[p] = s4.z | ((d4.z & 127) << 17);
                p = atomicAdd(&cur[d4.w >> 7], 1); ebuf[p] = s4.w | ((d4.w & 127) << 17);
            } else {
                for (int i = e; i < E && i < e + 4; i++) {
                    int s = src[i], d = dst[i];
                    int p = atomicAdd(&cur[d >> 7], 1);
                    ebuf[p] = s | ((d & 127) << 17);
                }
            }
        }
    } else {
        for (int c = threadIdx.x; c < PB_EDGES / 4; c += 256) {
            int e = base + c * 4;
            if (e + 3 < E) {
                int4 s4 = *(const int4*)(src + e);
                int p;
                p = atomicAdd(&cur[s4.x >> 7], 1); sbuf[p] = s4.x;
                p = atomicAdd(&cur[s4.y >> 7], 1); sbuf[p] = s4.y;
                p = atomicAdd(&cur[s4.z >> 7], 1); sbuf[p] = s4.z;
                p = atomicAdd(&cur[s4.w >> 7], 1); sbuf[p] = s4.w;
            } else {
                for (int i = e; i < E && i < e + 4; i++) {
                    int s = src[i];
                    int p = atomicAdd(&cur[s >> 7], 1);
                    sbuf[p] = s;
                }
            }
        }
    }
}

// ---- P4 (fused): k<NBIN: per-bin CSR + degree-sorted perm; k>=NBIN: outdeg ----
__global__ __launch_bounds__(256) void p4_comb(const int* __restrict__ ebuf,
                                               const int* __restrict__ sbuf,
                                               const int* __restrict__ bstart,
                                               int NBIN, int N, int E,
                                               int* __restrict__ indeg, int* __restrict__ coff,
                                               int* __restrict__ adj, int* __restrict__ outdeg,
                                               int* __restrict__ perm) {
    __shared__ int hist[128];
    __shared__ int sc[128];
    __shared__ int cur[128];
    __shared__ int lsrc[4096];
    __shared__ int dcnt[64];
    __shared__ int order[128];
    int kb = blockIdx.x;
    int tid = threadIdx.x;
    if (kb >= NBIN) {
        int k = kb - NBIN;
        const int* bstartS = bstart + (NBIN + 1);
        int s0 = bstartS[k], s1 = bstartS[k + 1];
        if (tid < 128) hist[tid] = 0;
        __syncthreads();
        for (int i = s0 + tid; i < s1; i += 256) atomicAdd(&hist[sbuf[i] & 127], 1);
        __syncthreads();
        if (tid < 128) {
            int node = k * W_BIN + tid;
            if (node < N) outdeg[node] = hist[tid];
        }
        return;
    }
    int k = kb;
    int s0 = bstart[k], s1 = bstart[k + 1];
    int M = s1 - s0;
    if (tid < 128) hist[tid] = 0;
    if (tid < 64) dcnt[tid] = 0;
    __syncthreads();
    for (int i = tid; i < M; i += 256) {
        int e = ebuf[s0 + i];
        atomicAdd(&hist[(e >> 17) & 127], 1);
    }
    __syncthreads();
    if (tid < 128) sc[tid] = hist[tid];
    __syncthreads();
    for (int o = 1; o < 128; o <<= 1) {
        int v = 0;
        if (tid < 128 && tid >= o) v = sc[tid - o];
        __syncthreads();
        if (tid < 128) sc[tid] += v;
        __syncthreads();
    }
    int valid = N - k * W_BIN;
    if (valid > 128) valid = 128;
    if (tid < 128) {
        int node = k * W_BIN + tid;
        if (node < N) {
            indeg[node] = hist[tid];
            coff[node] = s0 + sc[tid] - hist[tid];
        }
        cur[tid] = sc[tid] - hist[tid];
    }
    if (k == NBIN - 1 && tid == 0) coff[N] = E;
    // degree-class histogram for counting sort
    if (tid < valid) {
        int key = hist[tid]; if (key > 63) key = 63;
        atomicAdd(&dcnt[key], 1);
    }
    __syncthreads();
    if (tid == 0) {
        int a = 0;
        for (int i = 0; i < 64; i++) { int t = dcnt[i]; dcnt[i] = a; a += t; }
    }
    __syncthreads();
    if (tid < valid) {
        int key = hist[tid]; if (key > 63) key = 63;
        int p = atomicAdd(&dcnt[key], 1);
        order[p] = tid;
    }
    __syncthreads();
    if (tid < valid) perm[k * W_BIN + tid] = k * W_BIN + order[tid];
    // CSR scatter
    if (M <= 4096) {
        for (int i = tid; i < M; i += 256) {
            int e = ebuf[s0 + i];
            int p = atomicAdd(&cur[(e >> 17) & 127], 1);
            lsrc[p] = e & 0x1FFFF;
        }
        __syncthreads();
        for (int i = tid; i < M; i += 256) adj[s0 + i] = lsrc[i];
    } else {
        for (int i = tid; i < M; i += 256) {
            int e = ebuf[s0 + i];
            int p = atomicAdd(&cur[(e >> 17) & 127], 1);
            adj[s0 + p] = e & 0x1FFFF;
        }
    }
}

// ---- misc (fused): goffs boundary-detect + degree norms + Wt bf16 transpose ----
__global__ void misc_kernel(const int* __restrict__ gids,
                            const int* __restrict__ outdeg, const int* __restrict__ indeg,
                            const float* __restrict__ W1, const float* __restrict__ W2,
                            int N, int* __restrict__ goffs,
                            float* __restrict__ nrm_out, float* __restrict__ nrm_in,
                            unsigned short* __restrict__ Wt1, unsigned short* __restrict__ Wt2) {
    int i = blockIdx.x * blockDim.x + threadIdx.x;
    if (i <= N) {
        int prev = (i == 0) ? -1 : gids[i - 1];
        int cur = (i == N) ? NUM_G : gids[i];
        for (int g = prev + 1; g <= cur && g <= NUM_G; g++) goffs[g] = i;
    }
    if (i < N) {
        nrm_out[i] = rsqrtf(fmaxf((float)outdeg[i], 1.0f));
        nrm_in[i]  = rsqrtf(fmaxf((float)indeg[i], 1.0f));
    }
    if (i < 32768) {
        int sel = i >> 14;
        int idx = i & 16383;
        int k = idx >> 7, n = idx & 127;
        float v = (sel ? W2 : W1)[idx];
        (sel ? Wt2 : Wt1)[n * 128 + k] = (unsigned short)f2bf_bits(v);
    }
}

// ---- xsb[n] = bf16(h[n] * nrm_out[n]) : 16 lanes/node, 8 elems/lane ----
__global__ void scale_kernel(const float* __restrict__ h, const float* __restrict__ nrm_out,
                             uint32* __restrict__ xsb, int N) {
    int t = blockIdx.x * blockDim.x + threadIdx.x;
    int node = t >> 4, q = t & 15;
    if (node >= N) return;
    float ns = nrm_out[node];
    const float4* hv = (const float4*)(h + (size_t)node * 128 + q * 8);
    float4 a = hv[0], b = hv[1];
    a.x *= ns; a.y *= ns; a.z *= ns; a.w *= ns;
    b.x *= ns; b.y *= ns; b.z *= ns; b.w *= ns;
    uint4 o;
    o.x = pack2(a.x, a.y); o.y = pack2(a.z, a.w);
    o.z = pack2(b.x, b.y); o.w = pack2(b.z, b.w);
    ((uint4*)xsb)[(size_t)node * 16 + q] = o;
}

__device__ __forceinline__ void acc8(float* acc, uint4 u) {
    acc[0] += bflo(u.x); acc[1] += bfhi(u.x); acc[2] += bflo(u.y); acc[3] += bfhi(u.y);
    acc[4] += bflo(u.z); acc[5] += bfhi(u.z); acc[6] += bflo(u.w); acc[7] += bfhi(u.w);
}

// ---- aggregation: 16 lanes/node, nodes in degree-sorted perm order ----
__global__ void agg_kernel(const uint32* __restrict__ xsb, const int* __restrict__ adj,
                           const int* __restrict__ coff, const int* __restrict__ perm,
                           uint32* __restrict__ aggb, int N) {
    int t = blockIdx.x * blockDim.x + threadIdx.x;
    int gi = t >> 4;
    int q = t & 15;
    if (gi >= N) return;
    int node = perm[gi];
    int jb = coff[node], je = coff[node + 1];
    float acc[8];
#pragma unroll
    for (int i = 0; i < 8; i++) acc[i] = 0.f;
    const uint4* rows = (const uint4*)xsb;
    int j = jb;
    for (; j + 3 < je; j += 4) {
        int s0 = adj[j], s1 = adj[j + 1], s2 = adj[j + 2], s3 = adj[j + 3];
        uint4 u0 = rows[(size_t)s0 * 16 + q];
        uint4 u1 = rows[(size_t)s1 * 16 + q];
        uint4 u2 = rows[(size_t)s2 * 16 + q];
        uint4 u3 = rows[(size_t)s3 * 16 + q];
        acc8(acc, u0); acc8(acc, u1); acc8(acc, u2); acc8(acc, u3);
    }
    for (; j < je; j++) {
        uint4 u = rows[(size_t)adj[j] * 16 + q];
        acc8(acc, u);
    }
    uint4 o;
    o.x = pack2(acc[0], acc[1]); o.y = pack2(acc[2], acc[3]);
    o.z = pack2(acc[4], acc[5]); o.w = pack2(acc[6], acc[7]);
    ((uint4*)aggb)[(size_t)node * 16 + q] = o;
}

// ---- MFMA GEMM: 4 waves x 32 rows = 128 rows/block; B-frag shared by 2 row-tiles ----
__global__ __launch_bounds__(256) void gemm_mfma(const unsigned short* __restrict__ A,
                                                 const unsigned short* __restrict__ Wtg,
                                                 const float* __restrict__ bias,
                                                 const float* __restrict__ rowscale,
                                                 const float* __restrict__ postscale,
                                                 unsigned short* __restrict__ out,
                                                 int N, int do_relu) {
    __shared__ unsigned short Wl[128 * 136];
    for (int i = threadIdx.x; i < 2048; i += 256) {
        uint4 v = ((const uint4*)Wtg)[i];
        *(uint4*)&Wl[(i >> 4) * 136 + (i & 15) * 8] = v;
    }
    __syncthreads();

    int lane = threadIdx.x & 63;
    int wv = threadIdx.x >> 6;
    int col_l = lane & 15;
    int quad = lane >> 4;
    int r0w = blockIdx.x * 128 + wv * 32;
    if (r0w >= N) return;

    int arow0 = r0w + col_l;        if (arow0 >= N) arow0 = N - 1;
    int arow1 = r0w + 16 + col_l;   if (arow1 >= N) arow1 = N - 1;
    const unsigned short* Ar0 = A + (size_t)arow0 * 128;
    const unsigned short* Ar1 = A + (size_t)arow1 * 128;

    f32x4 acc[2][8];
#pragma unroll
    for (int rt = 0; rt < 2; rt++)
#pragma unroll
        for (int t = 0; t < 8; t++) {
            acc[rt][t][0] = 0.f; acc[rt][t][1] = 0.f;
            acc[rt][t][2] = 0.f; acc[rt][t][3] = 0.f;
        }

#pragma unroll
    for (int kk = 0; kk < 4; kk++) {
        bf16x8 a0 = *(const bf16x8*)(Ar0 + kk * 32 + quad * 8);
        bf16x8 a1 = *(const bf16x8*)(Ar1 + kk * 32 + quad * 8);
        const unsigned short* wb = &Wl[(size_t)col_l * 136 + kk * 32 + quad * 8];
#pragma unroll
        for (int t = 0; t < 8; t++) {
            bf16x8 b = *(const bf16x8*)(wb + (size_t)t * 16 * 136);
            acc[0][t] = __builtin_amdgcn_mfma_f32_16x16x32_bf16(a0, b, acc[0][t], 0, 0, 0);
            acc[1][t] = __builtin_amdgcn_mfma_f32_16x16x32_bf16(a1, b, acc[1][t], 0, 0, 0);
        }
    }

#pragma unroll
    for (int rt = 0; rt < 2; rt++) {
        int rbase = r0w + rt * 16;
        float s[4], p[4];
#pragma unroll
        for (int j = 0; j < 4; j++) {
            int rw = rbase + quad * 4 + j;
            bool ok = rw < N;
            s[j] = ok ? rowscale[ok ? rw : 0] : 0.f;
            p[j] = (postscale != nullptr && ok) ? postscale[rw] : 1.f;
        }
#pragma unroll
        for (int t = 0; t < 8; t++) {
            int c = t * 16 + col_l;
            float bia = bias[c];
#pragma unroll
            for (int j = 0; j < 4; j++) {
                int rw = rbase + quad * 4 + j;
                if (rw >= N) continue;
                float v = fmaf(s[j], acc[rt][t][j], bia);
                if (do_relu) v = fmaxf(v, 0.f);
                v *= p[j];
                out[(size_t)rw * 128 + c] = (unsigned short)f2bf_bits(v);
            }
        }
    }
}

// ---- fused per-graph mean + classifier head ----
__global__ __launch_bounds__(1024) void mean_final(const uint32* __restrict__ x2b,
                                                   const int* __restrict__ goffs,
                                                   const float* __restrict__ perm,
                                                   const float* __restrict__ Wc,
                                                   const float* __restrict__ bc,
                                                   float* __restrict__ out) {
    __shared__ float red[16][128];
    __shared__ float hrow[128];
    int g = blockIdx.x;
    int cp = threadIdx.x & 63;
    int j = threadIdx.x >> 6;  // 0..15
    int s = goffs[g], e = goffs[g + 1];
    float a0 = 0.f, a1 = 0.f;
    for (int r = s + j; r < e; r += 16) {
        uint32 u = x2b[(size_t)r * 64 + cp];
        a0 += bflo(u); a1 += bfhi(u);
    }
    red[j][cp * 2] = a0;
    red[j][cp * 2 + 1] = a1;
    __syncthreads();
    if (j == 0) {
        float t0 = 0.f, t1 = 0.f;
#pragma unroll
        for (int jj = 0; jj < 16; jj++) { t0 += red[jj][cp * 2]; t1 += red[jj][cp * 2 + 1]; }
        float cnt = fmaxf((float)(e - s), 1.0f);
        hrow[cp * 2] = t0 / cnt;
        hrow[cp * 2 + 1] = t1 / cnt;
    }
    __syncthreads();
    if (threadIdx.x < 10) {
        int c = threadIdx.x;
        float acc = bc[c];
#pragma unroll 8
        for (int k = 0; k < 128; k++) acc = fmaf(hrow[k], Wc[k * 10 + c], acc);
        const float* prow = perm + g * 64;
#pragma unroll 8
        for (int p = 0; p < 64; p++) acc = fmaf(prow[p], Wc[(128 + p) * 10 + c], acc);
        out[g * 10 + c] = acc;
    }
}

extern "C" void kernel_launch(void* const* d_in, const int* in_sizes, int n_in,
                              void* d_out, int out_size, void* d_ws, size_t ws_size,
                              hipStream_t stream) {
    const float* h    = (const float*)d_in[0];
    const float* perm = (const float*)d_in[1];
    const float* W1   = (const float*)d_in[2];
    const float* b1   = (const float*)d_in[3];
    const float* W2   = (const float*)d_in[4];
    const float* b2   = (const float*)d_in[5];
    const float* Wc   = (const float*)d_in[6];
    const float* bc   = (const float*)d_in[7];
    const int* src    = (const int*)d_in[8];
    const int* dst    = (const int*)d_in[9];
    const int* gids   = (const int*)d_in[10];
    float* out = (float*)d_out;

    const int N = in_sizes[0] / 128;
    const int E = in_sizes[8];
    const int G = NUM_G, H = 128;
    const int B = (E + PB_EDGES - 1) / PB_EDGES;
    const int NBIN = (N + W_BIN - 1) / W_BIN;

    char* w = (char*)d_ws;
    size_t off = 0;
    auto alloc = [&](size_t bytes) -> void* {
        void* p = w + off;
        off = (off + bytes + 255) & ~(size_t)255;
        return p;
    };
    uint32* xsb   = (uint32*)alloc((size_t)N * H * 2);  // bf16 scaled in; later x2 out
    uint32* aggb  = (uint32*)alloc((size_t)N * H * 2);  // bf16 agg out (both layers)
    uint32* x1b   = (uint32*)alloc((size_t)N * H * 2);  // bf16 layer-1 out
    unsigned short* Wt1 = (unsigned short*)alloc(16384 * 2);
    unsigned short* Wt2 = (unsigned short*)alloc(16384 * 2);
    int*    adj     = (int*)alloc((size_t)E * 4);
    int*    coff    = (int*)alloc((size_t)(N + 1) * 4);
    int*    indeg   = (int*)alloc((size_t)N * 4);
    int*    outdeg  = (int*)alloc((size_t)N * 4);
    int*    nperm   = (int*)alloc((size_t)N * 4);   // degree-sorted node order
    float*  nrm_out = (float*)alloc((size_t)N * 4);
    float*  nrm_in  = (float*)alloc((size_t)N * 4);
    int*    goffs   = (int*)alloc((size_t)(G + 1) * 4);

    // Build temporaries alias aggb (dead until agg_kernel writes it).
    char* tmp = (char*)aggb;
    size_t toff = 0;
    auto talloc = [&](size_t bytes) -> void* {
        void* p = tmp + toff;
        toff = (toff + bytes + 255) & ~(size_t)255;
        return p;
    };
    int*  ebuf   = (int*)talloc((size_t)E * 4);   // packed src | dstlow<<17
    int*  sbuf   = (int*)talloc((size_t)E * 4);
    int*  bh     = (int*)talloc((size_t)2 * B * NBIN * 4);
    int*  curs   = (int*)talloc((size_t)2 * B * NBIN * 4);
    int*  tot    = (int*)talloc((size_t)2 * NBIN * 4);
    int*  bstart = (int*)talloc((size_t)2 * (NBIN + 1) * 4);

    // ---- atomic-free graph build ----
    p1_hist<<<2 * B, 256, 0, stream>>>(src, dst, E, NBIN, B, bh);
    p2a_tot<<<2 * NBIN, 256, 0, stream>>>(bh, NBIN, B, tot);
    p2c_cursor<<<2 * NBIN, 512, 0, stream>>>(bh, tot, NBIN, B, E, bstart, curs);
    p3_scatter<<<2 * B, 256, 0, stream>>>(src, dst, E, NBIN, B, curs, ebuf, sbuf);
    p4_comb<<<2 * NBIN, 256, 0, stream>>>(ebuf, sbuf, bstart, NBIN, N, E,
                                          indeg, coff, adj, outdeg, nperm);

    misc_kernel<<<(N + 1 + 255) / 256, 256, 0, stream>>>(gids, outdeg, indeg, W1, W2, N,
                                                         goffs, nrm_out, nrm_in, Wt1, Wt2);

    // layer 1
    scale_kernel<<<(N * 16 + 255) / 256, 256, 0, stream>>>(h, nrm_out, xsb, N);
    agg_kernel<<<(N * 16 + 255) / 256, 256, 0, stream>>>(xsb, adj, coff, nperm, aggb, N);
    gemm_mfma<<<(N + 127) / 128, 256, 0, stream>>>((const unsigned short*)aggb, Wt1, b1,
                                                   nrm_in, nrm_out,
                                                   (unsigned short*)x1b, N, 1);

    // layer 2 (output bf16 into xsb, dead after agg1)
    agg_kernel<<<(N * 16 + 255) / 256, 256, 0, stream>>>(x1b, adj, coff, nperm, aggb, N);
    gemm_mfma<<<(N + 127) / 128, 256, 0, stream>>>((const unsigned short*)aggb, Wt2, b2,
                                                   nrm_in, nullptr,
                                                   (unsigned short*)xsb, N, 0);

    // fused readout
    mean_final<<<G, 1024, 0, stream>>>(xsb, goffs, perm, Wc, bc, out);
}

// Round 12
// 347.707 us; speedup vs baseline: 1.1027x; 1.1027x over previous
//
#include <hip/hip_runtime.h>

// GCN: 2x GraphConv(norm='both') + per-graph mean + [hg|perm] @ Wc + bc
// N=100000, E=1600000, D=H=128, P=64, C=10, G=128
// R12: R10 structure (counter-verified agg optimum: unroll-4, row-major) with
// fixed-cost trims: norms computed inside p4 (no indeg/outdeg arrays),
// goffs+Wt folded into p1 (11 dispatches). R9 chunking / R11 degree-sort both
// regressed agg (see journal) — do not reintroduce.

#define NUM_G 128
#define PB_EDGES 4096   // edges per partition block
#define W_BIN 128       // nodes per bin (key>>7)

typedef unsigned int uint32;
typedef short bf16x8 __attribute__((ext_vector_type(8)));
typedef float f32x4 __attribute__((ext_vector_type(4)));

__device__ __forceinline__ float bflo(uint32 u) { return __uint_as_float(u << 16); }
__device__ __forceinline__ float bfhi(uint32 u) { return __uint_as_float(u & 0xffff0000u); }
__device__ __forceinline__ uint32 f2bf_bits(float f) {  // RNE
    uint32 b = __float_as_uint(f);
    return (b + 0x7fffu + ((b >> 16) & 1u)) >> 16;
}
__device__ __forceinline__ uint32 pack2(float a, float b) {
    return f2bf_bits(a) | (f2bf_bits(b) << 16);
}

// ---- P1: blocks [0,2B): per-block LDS histogram of key>>7 (pipe0=dst, pipe1=src).
// ---- blocks [2B, 2B+GB): goffs boundary detect. blocks [2B+GB, 2B+GB+128): Wt. ----
__global__ __launch_bounds__(256) void p1_hist(const int* __restrict__ src,
                                               const int* __restrict__ dst, int E,
                                               int NBIN, int B, int GB, int N,
                                               const int* __restrict__ gids,
                                               const float* __restrict__ W1,
                                               const float* __restrict__ W2,
                                               int* __restrict__ bh,
                                               int* __restrict__ goffs,
                                               unsigned short* __restrict__ Wt1,
                                               unsigned short* __restrict__ Wt2) {
    int b = blockIdx.x;
    if (b >= 2 * B) {
        int eb = b - 2 * B;
        if (eb < GB) {  // goffs
            int i = eb * 256 + threadIdx.x;
            if (i <= N) {
                int prev = (i == 0) ? -1 : gids[i - 1];
                int cur = (i == N) ? NUM_G : gids[i];
                for (int g = prev + 1; g <= cur && g <= NUM_G; g++) goffs[g] = i;
            }
        } else {  // Wt transpose+cast: 128 blocks x 256 threads = 32768
            int i = (eb - GB) * 256 + threadIdx.x;
            int sel = i >> 14;
            int idx = i & 16383;
            int k = idx >> 7, n = idx & 127;
            float v = (sel ? W2 : W1)[idx];
            (sel ? Wt2 : Wt1)[n * 128 + k] = (unsigned short)f2bf_bits(v);
        }
        return;
    }
    __shared__ int hist[1024];
    int pipe = (b >= B) ? 1 : 0;
    int bb = pipe ? b - B : b;
    const int* key = pipe ? src : dst;
    for (int i = threadIdx.x; i < NBIN; i += 256) hist[i] = 0;
    __syncthreads();
    int base = bb * PB_EDGES;
    for (int c = threadIdx.x; c < PB_EDGES / 4; c += 256) {
        int e = base + c * 4;
        if (e + 3 < E) {
            int4 k4 = *(const int4*)(key + e);
            atomicAdd(&hist[k4.x >> 7], 1);
            atomicAdd(&hist[k4.y >> 7], 1);
            atomicAdd(&hist[k4.z >> 7], 1);
            atomicAdd(&hist[k4.w >> 7], 1);
        } else {
            for (int i = e; i < E && i < e + 4; i++) atomicAdd(&hist[key[i] >> 7], 1);
        }
    }
    __syncthreads();
    int* outp = bh + (size_t)pipe * NBIN * B;
    for (int k = threadIdx.x; k < NBIN; k += 256)
        outp[(size_t)k * B + bb] = hist[k];
}

// ---- P2a: tot[pipe][k] = sum_b bh[pipe][k][b] ----
__global__ __launch_bounds__(256) void p2a_tot(const int* __restrict__ bh, int NBIN, int B,
                                               int* __restrict__ tot) {
    __shared__ int sc[256];
    int k = blockIdx.x % NBIN, pipe = blockIdx.x / NBIN;
    const int* row = bh + (size_t)pipe * NBIN * B + (size_t)k * B;
    int acc = 0;
    for (int b = threadIdx.x; b < B; b += 256) acc += row[b];
    sc[threadIdx.x] = acc;
    __syncthreads();
    for (int o = 128; o > 0; o >>= 1) {
        if (threadIdx.x < o) sc[threadIdx.x] += sc[threadIdx.x + o];
        __syncthreads();
    }
    if (threadIdx.x == 0) tot[pipe * NBIN + k] = sc[0];
}

// ---- P2c: block (pipe,k): base = prefix(tot) inline; write bstart; scan bh over B ----
__global__ __launch_bounds__(512) void p2c_cursor(const int* __restrict__ bh,
                                                  const int* __restrict__ tot,
                                                  int NBIN, int B, int E,
                                                  int* __restrict__ bstart,
                                                  int* __restrict__ curs) {
    __shared__ int sc[512];
    int k = blockIdx.x % NBIN, pipe = blockIdx.x / NBIN;
    int i = threadIdx.x;
    int pacc = 0;
    for (int kk = i; kk < k; kk += 512) pacc += tot[pipe * NBIN + kk];
    sc[i] = pacc;
    __syncthreads();
    for (int o = 256; o > 0; o >>= 1) {
        if (i < o) sc[i] += sc[i + o];
        __syncthreads();
    }
    int base = sc[0];
    __syncthreads();
    if (i == 0) {
        bstart[pipe * (NBIN + 1) + k] = base;
        if (k == 0) bstart[pipe * (NBIN + 1) + NBIN] = E;
    }
    const int* row = bh + (size_t)pipe * NBIN * B + (size_t)k * B;
    int v = (i < B) ? row[i] : 0;
    sc[i] = v;
    __syncthreads();
    for (int o = 1; o < 512; o <<= 1) {
        int t = (i >= o) ? sc[i - o] : 0;
        __syncthreads();
        sc[i] += t;
        __syncthreads();
    }
    if (i < B)
        curs[(size_t)pipe * B * NBIN + (size_t)i * NBIN + k] = base + sc[i] - v;
}

// ---- P3: scatter edges into bin-partitioned buffers (LDS cursors) ----
// pipe0 entry: src | (dst&127)<<17  (src < 2^17; dst low bits for in-bin CSR)
__global__ __launch_bounds__(256) void p3_scatter(const int* __restrict__ src,
                                                  const int* __restrict__ dst, int E,
                                                  int NBIN, int B, const int* __restrict__ curs,
                                                  int* __restrict__ ebuf, int* __restrict__ sbuf) {
    __shared__ int cur[1024];
    int b = blockIdx.x;
    int pipe = (b >= B) ? 1 : 0;
    int bb = pipe ? b - B : b;
    const int* crow = curs + (size_t)pipe * B * NBIN + (size_t)bb * NBIN;
    for (int i = threadIdx.x; i < NBIN; i += 256) cur[i] = crow[i];
    __syncthreads();
    int base = bb * PB_EDGES;
    if (!pipe) {
        for (int c = threadIdx.x; c < PB_EDGES / 4; c += 256) {
            int e = base + c * 4;
            if (e + 3 < E) {
                int4 s4 = *(const int4*)(src + e);
                int4 d4 = *(const int4*)(dst + e);
                int p;
                p = atomicAdd(&cur[d4.x >> 7], 1); ebuf[p] = s4.x | ((d4.x & 127) << 17);
                p = atomicAdd(&cur[d4.y >> 7], 1); ebuf[p] = s4.y | ((d4.y & 127) << 17);
                p = atomicAdd(&cur[d4.z >> 7], 1); ebuf[p] = s4.z | ((d4.z & 127) << 17);
                p = atomicAdd(&cur[d4.w >> 7], 1); ebuf[p] = s4.w | ((d4.w & 127) << 17);
            } else {
                for (int i = e; i < E && i < e + 4; i++) {
                    int s = src[i], d = dst[i];
                    int p = atomicAdd(&cur[d >> 7], 1);
                    ebuf[p] = s | ((d & 127) << 17);
                }
            }
        }
    } else {
        for (int c = threadIdx.x; c < PB_EDGES / 4; c += 256) {
            int e = base + c * 4;
            if (e + 3 < E) {
                int4 s4 = *(const int4*)(src + e);
                int p;
                p = atomicAdd(&cur[s4.x >> 7], 1); sbuf[p] = s4.x;
                p = atomicAdd(&cur[s4.y >> 7], 1); sbuf[p] = s4.y;
                p = atomicAdd(&cur[s4.z >> 7], 1); sbuf[p] = s4.z;
                p = atomicAdd(&cur[s4.w >> 7], 1); sbuf[p] = s4.w;
            } else {
                for (int i = e; i < E && i < e + 4; i++) {
                    int s = src[i];
                    int p = atomicAdd(&cur[s >> 7], 1);
                    sbuf[p] = s;
                }
            }
        }
    }
}

// ---- P4 (fused): k<NBIN: per-bin CSR + nrm_in; k>=NBIN: outdeg hist -> nrm_out ----
__global__ __launch_bounds__(256) void p4_comb(const int* __restrict__ ebuf,
                                               const int* __restrict__ sbuf,
                                               const int* __restrict__ bstart,
                                               int NBIN, int N, int E,
                                               int* __restrict__ coff,
                                               int* __restrict__ adj,
                                               float* __restrict__ nrm_in,
                                               float* __restrict__ nrm_out) {
    __shared__ int hist[128];
    __shared__ int sc[128];
    __shared__ int cur[128];
    __shared__ int lsrc[4096];
    int kb = blockIdx.x;
    int tid = threadIdx.x;
    if (kb >= NBIN) {
        int k = kb - NBIN;
        const int* bstartS = bstart + (NBIN + 1);
        int s0 = bstartS[k], s1 = bstartS[k + 1];
        if (tid < 128) hist[tid] = 0;
        __syncthreads();
        for (int i = s0 + tid; i < s1; i += 256) atomicAdd(&hist[sbuf[i] & 127], 1);
        __syncthreads();
        if (tid < 128) {
            int node = k * W_BIN + tid;
            if (node < N) nrm_out[node] = rsqrtf(fmaxf((float)hist[tid], 1.0f));
        }
        return;
    }
    int k = kb;
    int s0 = bstart[k], s1 = bstart[k + 1];
    int M = s1 - s0;
    if (tid < 128) hist[tid] = 0;
    __syncthreads();
    for (int i = tid; i < M; i += 256) {
        int e = ebuf[s0 + i];
        atomicAdd(&hist[(e >> 17) & 127], 1);
    }
    __syncthreads();
    if (tid < 128) sc[tid] = hist[tid];
    __syncthreads();
    for (int o = 1; o < 128; o <<= 1) {
        int v = 0;
        if (tid < 128 && tid >= o) v = sc[tid - o];
        __syncthreads();
        if (tid < 128) sc[tid] += v;
        __syncthreads();
    }
    if (tid < 128) {
        int node = k * W_BIN + tid;
        if (node < N) {
            coff[node] = s0 + sc[tid] - hist[tid];
            nrm_in[node] = rsqrtf(fmaxf((float)hist[tid], 1.0f));
        }
        cur[tid] = sc[tid] - hist[tid];
    }
    if (k == NBIN - 1 && tid == 0) coff[N] = E;
    __syncthreads();
    if (M <= 4096) {
        for (int i = tid; i < M; i += 256) {
            int e = ebuf[s0 + i];
            int p = atomicAdd(&cur[(e >> 17) & 127], 1);
            lsrc[p] = e & 0x1FFFF;
        }
        __syncthreads();
        for (int i = tid; i < M; i += 256) adj[s0 + i] = lsrc[i];
    } else {
        for (int i = tid; i < M; i += 256) {
            int e = ebuf[s0 + i];
            int p = atomicAdd(&cur[(e >> 17) & 127], 1);
            adj[s0 + p] = e & 0x1FFFF;
        }
    }
}

// ---- xsb[n] = bf16(h[n] * nrm_out[n]) : 16 lanes/node, 8 elems/lane ----
__global__ void scale_kernel(const float* __restrict__ h, const float* __restrict__ nrm_out,
                             uint32* __restrict__ xsb, int N) {
    int t = blockIdx.x * blockDim.x + threadIdx.x;
    int node = t >> 4, q = t & 15;
    if (node >= N) return;
    float ns = nrm_out[node];
    const float4* hv = (const float4*)(h + (size_t)node * 128 + q * 8);
    float4 a = hv[0], b = hv[1];
    a.x *= ns; a.y *= ns; a.z *= ns; a.w *= ns;
    b.x *= ns; b.y *= ns; b.z *= ns; b.w *= ns;
    uint4 o;
    o.x = pack2(a.x, a.y); o.y = pack2(a.z, a.w);
    o.z = pack2(b.x, b.y); o.w = pack2(b.z, b.w);
    ((uint4*)xsb)[(size_t)node * 16 + q] = o;
}

__device__ __forceinline__ void acc8(float* acc, uint4 u) {
    acc[0] += bflo(u.x); acc[1] += bfhi(u.x); acc[2] += bflo(u.y); acc[3] += bfhi(u.y);
    acc[4] += bflo(u.z); acc[5] += bfhi(u.z); acc[6] += bflo(u.w); acc[7] += bfhi(u.w);
}

// ---- aggregation: 16 lanes/node, row-major 256B rows, unroll-4 (R8 optimum) ----
__global__ void agg_kernel(const uint32* __restrict__ xsb, const int* __restrict__ adj,
                           const int* __restrict__ coff, uint32* __restrict__ aggb, int N) {
    int t = blockIdx.x * blockDim.x + threadIdx.x;
    int node = t >> 4;
    int q = t & 15;
    if (node >= N) return;
    int jb = coff[node], je = coff[node + 1];
    float acc[8];
#pragma unroll
    for (int i = 0; i < 8; i++) acc[i] = 0.f;
    const uint4* rows = (const uint4*)xsb;
    int j = jb;
    for (; j + 3 < je; j += 4) {
        int s0 = adj[j], s1 = adj[j + 1], s2 = adj[j + 2], s3 = adj[j + 3];
        uint4 u0 = rows[(size_t)s0 * 16 + q];
        uint4 u1 = rows[(size_t)s1 * 16 + q];
        uint4 u2 = rows[(size_t)s2 * 16 + q];
        uint4 u3 = rows[(size_t)s3 * 16 + q];
        acc8(acc, u0); acc8(acc, u1); acc8(acc, u2); acc8(acc, u3);
    }
    for (; j < je; j++) {
        uint4 u = rows[(size_t)adj[j] * 16 + q];
        acc8(acc, u);
    }
    uint4 o;
    o.x = pack2(acc[0], acc[1]); o.y = pack2(acc[2], acc[3]);
    o.z = pack2(acc[4], acc[5]); o.w = pack2(acc[6], acc[7]);
    ((uint4*)aggb)[(size_t)node * 16 + q] = o;
}

// ---- MFMA GEMM: 4 waves x 32 rows = 128 rows/block; B-frag shared by 2 row-tiles ----
__global__ __launch_bounds__(256) void gemm_mfma(const unsigned short* __restrict__ A,
                                                 const unsigned short* __restrict__ Wtg,
                                                 const float* __restrict__ bias,
                                                 const float* __restrict__ rowscale,
                                                 const float* __restrict__ postscale,
                                                 unsigned short* __restrict__ out,
                                                 int N, int do_relu) {
    __shared__ unsigned short Wl[128 * 136];
    for (int i = threadIdx.x; i < 2048; i += 256) {
        uint4 v = ((const uint4*)Wtg)[i];
        *(uint4*)&Wl[(i >> 4) * 136 + (i & 15) * 8] = v;
    }
    __syncthreads();

    int lane = threadIdx.x & 63;
    int wv = threadIdx.x >> 6;
    int col_l = lane & 15;
    int quad = lane >> 4;
    int r0w = blockIdx.x * 128 + wv * 32;
    if (r0w >= N) return;

    int arow0 = r0w + col_l;        if (arow0 >= N) arow0 = N - 1;
    int arow1 = r0w + 16 + col_l;   if (arow1 >= N) arow1 = N - 1;
    const unsigned short* Ar0 = A + (size_t)arow0 * 128;
    const unsigned short* Ar1 = A + (size_t)arow1 * 128;

    f32x4 acc[2][8];
#pragma unroll
    for (int rt = 0; rt < 2; rt++)
#pragma unroll
        for (int t = 0; t < 8; t++) {
            acc[rt][t][0] = 0.f; acc[rt][t][1] = 0.f;
            acc[rt][t][2] = 0.f; acc[rt][t][3] = 0.f;
        }

#pragma unroll
    for (int kk = 0; kk < 4; kk++) {
        bf16x8 a0 = *(const bf16x8*)(Ar0 + kk * 32 + quad * 8);
        bf16x8 a1 = *(const bf16x8*)(Ar1 + kk * 32 + quad * 8);
        const unsigned short* wb = &Wl[(size_t)col_l * 136 + kk * 32 + quad * 8];
#pragma unroll
        for (int t = 0; t < 8; t++) {
            bf16x8 b = *(const bf16x8*)(wb + (size_t)t * 16 * 136);
            acc[0][t] = __builtin_amdgcn_mfma_f32_16x16x32_bf16(a0, b, acc[0][t], 0, 0, 0);
            acc[1][t] = __builtin_amdgcn_mfma_f32_16x16x32_bf16(a1, b, acc[1][t], 0, 0, 0);
        }
    }

#pragma unroll
    for (int rt = 0; rt < 2; rt++) {
        int rbase = r0w + rt * 16;
        float s[4], p[4];
#pragma unroll
        for (int j = 0; j < 4; j++) {
            int rw = rbase + quad * 4 + j;
            bool ok = rw < N;
            s[j] = ok ? rowscale[ok ? rw : 0] : 0.f;
            p[j] = (postscale != nullptr && ok) ? postscale[rw] : 1.f;
        }
#pragma unroll
        for (int t = 0; t < 8; t++) {
            int c = t * 16 + col_l;
            float bia = bias[c];
#pragma unroll
            for (int j = 0; j < 4; j++) {
                int rw = rbase + quad * 4 + j;
                if (rw >= N) continue;
                float v = fmaf(s[j], acc[rt][t][j], bia);
                if (do_relu) v = fmaxf(v, 0.f);
                v *= p[j];
                out[(size_t)rw * 128 + c] = (unsigned short)f2bf_bits(v);
            }
        }
    }
}

// ---- fused per-graph mean + classifier head ----
__global__ __launch_bounds__(1024) void mean_final(const uint32* __restrict__ x2b,
                                                   const int* __restrict__ goffs,
                                                   const float* __restrict__ perm,
                                                   const float* __restrict__ Wc,
                                                   const float* __restrict__ bc,
                                                   float* __restrict__ out) {
    __shared__ float red[16][128];
    __shared__ float hrow[128];
    int g = blockIdx.x;
    int cp = threadIdx.x & 63;
    int j = threadIdx.x >> 6;  // 0..15
    int s = goffs[g], e = goffs[g + 1];
    float a0 = 0.f, a1 = 0.f;
    for (int r = s + j; r < e; r += 16) {
        uint32 u = x2b[(size_t)r * 64 + cp];
        a0 += bflo(u); a1 += bfhi(u);
    }
    red[j][cp * 2] = a0;
    red[j][cp * 2 + 1] = a1;
    __syncthreads();
    if (j == 0) {
        float t0 = 0.f, t1 = 0.f;
#pragma unroll
        for (int jj = 0; jj < 16; jj++) { t0 += red[jj][cp * 2]; t1 += red[jj][cp * 2 + 1]; }
        float cnt = fmaxf((float)(e - s), 1.0f);
        hrow[cp * 2] = t0 / cnt;
        hrow[cp * 2 + 1] = t1 / cnt;
    }
    __syncthreads();
    if (threadIdx.x < 10) {
        int c = threadIdx.x;
        float acc = bc[c];
#pragma unroll 8
        for (int k = 0; k < 128; k++) acc = fmaf(hrow[k], Wc[k * 10 + c], acc);
        const float* prow = perm + g * 64;
#pragma unroll 8
        for (int p = 0; p < 64; p++) acc = fmaf(prow[p], Wc[(128 + p) * 10 + c], acc);
        out[g * 10 + c] = acc;
    }
}

extern "C" void kernel_launch(void* const* d_in, const int* in_sizes, int n_in,
                              void* d_out, int out_size, void* d_ws, size_t ws_size,
                              hipStream_t stream) {
    const float* h    = (const float*)d_in[0];
    const float* perm = (const float*)d_in[1];
    const float* W1   = (const float*)d_in[2];
    const float* b1   = (const float*)d_in[3];
    const float* W2   = (const float*)d_in[4];
    const float* b2   = (const float*)d_in[5];
    const float* Wc   = (const float*)d_in[6];
    const float* bc   = (const float*)d_in[7];
    const int* src    = (const int*)d_in[8];
    const int* dst    = (const int*)d_in[9];
    const int* gids   = (const int*)d_in[10];
    float* out = (float*)d_out;

    const int N = in_sizes[0] / 128;
    const int E = in_sizes[8];
    const int G = NUM_G, H = 128;
    const int B = (E + PB_EDGES - 1) / PB_EDGES;
    const int NBIN = (N + W_BIN - 1) / W_BIN;
    const int GB = (N + 1 + 255) / 256;   // goffs blocks

    char* w = (char*)d_ws;
    size_t off = 0;
    auto alloc = [&](size_t bytes) -> void* {
        void* p = w + off;
        off = (off + bytes + 255) & ~(size_t)255;
        return p;
    };
    uint32* xsb   = (uint32*)alloc((size_t)N * H * 2);  // bf16 scaled in; later x2 out
    uint32* aggb  = (uint32*)alloc((size_t)N * H * 2);  // bf16 agg out (both layers)
    uint32* x1b   = (uint32*)alloc((size_t)N * H * 2);  // bf16 layer-1 out
    unsigned short* Wt1 = (unsigned short*)alloc(16384 * 2);
    unsigned short* Wt2 = (unsigned short*)alloc(16384 * 2);
    int*    adj     = (int*)alloc((size_t)E * 4);
    int*    coff    = (int*)alloc((size_t)(N + 1) * 4);
    float*  nrm_out = (float*)alloc((size_t)N * 4);
    float*  nrm_in  = (float*)alloc((size_t)N * 4);
    int*    goffs   = (int*)alloc((size_t)(G + 1) * 4);

    // Build temporaries alias aggb (dead until agg_kernel writes it).
    char* tmp = (char*)aggb;
    size_t toff = 0;
    auto talloc = [&](size_t bytes) -> void* {
        void* p = tmp + toff;
        toff = (toff + bytes + 255) & ~(size_t)255;
        return p;
    };
    int*  ebuf   = (int*)talloc((size_t)E * 4);   // packed src | dstlow<<17
    int*  sbuf   = (int*)talloc((size_t)E * 4);
    int*  bh     = (int*)talloc((size_t)2 * B * NBIN * 4);
    int*  curs   = (int*)talloc((size_t)2 * B * NBIN * 4);
    int*  tot    = (int*)talloc((size_t)2 * NBIN * 4);
    int*  bstart = (int*)talloc((size_t)2 * (NBIN + 1) * 4);

    // ---- atomic-free graph build (+ goffs + Wt piggybacked on p1) ----
    p1_hist<<<2 * B + GB + 128, 256, 0, stream>>>(src, dst, E, NBIN, B, GB, N,
                                                  gids, W1, W2, bh, goffs, Wt1, Wt2);
    p2a_tot<<<2 * NBIN, 256, 0, stream>>>(bh, NBIN, B, tot);
    p2c_cursor<<<2 * NBIN, 512, 0, stream>>>(bh, tot, NBIN, B, E, bstart, curs);
    p3_scatter<<<2 * B, 256, 0, stream>>>(src, dst, E, NBIN, B, curs, ebuf, sbuf);
    p4_comb<<<2 * NBIN, 256, 0, stream>>>(ebuf, sbuf, bstart, NBIN, N, E,
                                          coff, adj, nrm_in, nrm_out);

    // layer 1
    scale_kernel<<<(N * 16 + 255) / 256, 256, 0, stream>>>(h, nrm_out, xsb, N);
    agg_kernel<<<(N * 16 + 255) / 256, 256, 0, stream>>>(xsb, adj, coff, aggb, N);
    gemm_mfma<<<(N + 127) / 128, 256, 0, stream>>>((const unsigned short*)aggb, Wt1, b1,
                                                   nrm_in, nrm_out,
                                                   (unsigned short*)x1b, N, 1);

    // layer 2 (output bf16 into xsb, dead after agg1)
    agg_kernel<<<(N * 16 + 255) / 256, 256, 0, stream>>>(x1b, adj, coff, aggb, N);
    gemm_mfma<<<(N + 127) / 128, 256, 0, stream>>>((const unsigned short*)aggb, Wt2, b2,
                                                   nrm_in, nullptr,
                                                   (unsigned short*)xsb, N, 0);

    // fused readout
    mean_final<<<G, 1024, 0, stream>>>(xsb, goffs, perm, Wc, bc, out);
}

// Round 13
// 333.031 us; speedup vs baseline: 1.1513x; 1.0441x over previous
//
#include <hip/hip_runtime.h>

// GCN: 2x GraphConv(norm='both') + per-graph mean + [hg|perm] @ Wc + bc
// N=100000, E=1600000, D=H=128, P=64, C=10, G=128
// R13: build-family compression: PB_EDGES 8192, W_BIN 256 (longer scatter runs,
// half the fine-sort blocks), sbuf as uint8. Core agg/gemm frozen at the R12
// counter-verified optimum (R9 chunking / R11 degree-sort regressed — journal).

#define NUM_G 128
#define PB_EDGES 8192   // edges per partition block
#define W_BIN 256       // nodes per bin (key>>8)

typedef unsigned int uint32;
typedef unsigned char uint8;
typedef short bf16x8 __attribute__((ext_vector_type(8)));
typedef float f32x4 __attribute__((ext_vector_type(4)));

__device__ __forceinline__ float bflo(uint32 u) { return __uint_as_float(u << 16); }
__device__ __forceinline__ float bfhi(uint32 u) { return __uint_as_float(u & 0xffff0000u); }
__device__ __forceinline__ uint32 f2bf_bits(float f) {  // RNE
    uint32 b = __float_as_uint(f);
    return (b + 0x7fffu + ((b >> 16) & 1u)) >> 16;
}
__device__ __forceinline__ uint32 pack2(float a, float b) {
    return f2bf_bits(a) | (f2bf_bits(b) << 16);
}

// ---- P1: blocks [0,2B): per-block LDS histogram of key>>8 (pipe0=dst, pipe1=src).
// ---- blocks [2B, 2B+GB): goffs boundary detect. blocks [2B+GB, 2B+GB+128): Wt. ----
__global__ __launch_bounds__(256) void p1_hist(const int* __restrict__ src,
                                               const int* __restrict__ dst, int E,
                                               int NBIN, int B, int GB, int N,
                                               const int* __restrict__ gids,
                                               const float* __restrict__ W1,
                                               const float* __restrict__ W2,
                                               int* __restrict__ bh,
                                               int* __restrict__ goffs,
                                               unsigned short* __restrict__ Wt1,
                                               unsigned short* __restrict__ Wt2) {
    int b = blockIdx.x;
    if (b >= 2 * B) {
        int eb = b - 2 * B;
        if (eb < GB) {  // goffs
            int i = eb * 256 + threadIdx.x;
            if (i <= N) {
                int prev = (i == 0) ? -1 : gids[i - 1];
                int cur = (i == N) ? NUM_G : gids[i];
                for (int g = prev + 1; g <= cur && g <= NUM_G; g++) goffs[g] = i;
            }
        } else {  // Wt transpose+cast: 128 blocks x 256 threads = 32768
            int i = (eb - GB) * 256 + threadIdx.x;
            int sel = i >> 14;
            int idx = i & 16383;
            int k = idx >> 7, n = idx & 127;
            float v = (sel ? W2 : W1)[idx];
            (sel ? Wt2 : Wt1)[n * 128 + k] = (unsigned short)f2bf_bits(v);
        }
        return;
    }
    __shared__ int hist[512];
    int pipe = (b >= B) ? 1 : 0;
    int bb = pipe ? b - B : b;
    const int* key = pipe ? src : dst;
    for (int i = threadIdx.x; i < NBIN; i += 256) hist[i] = 0;
    __syncthreads();
    int base = bb * PB_EDGES;
    for (int c = threadIdx.x; c < PB_EDGES / 4; c += 256) {
        int e = base + c * 4;
        if (e + 3 < E) {
            int4 k4 = *(const int4*)(key + e);
            atomicAdd(&hist[k4.x >> 8], 1);
            atomicAdd(&hist[k4.y >> 8], 1);
            atomicAdd(&hist[k4.z >> 8], 1);
            atomicAdd(&hist[k4.w >> 8], 1);
        } else {
            for (int i = e; i < E && i < e + 4; i++) atomicAdd(&hist[key[i] >> 8], 1);
        }
    }
    __syncthreads();
    int* outp = bh + (size_t)pipe * NBIN * B;
    for (int k = threadIdx.x; k < NBIN; k += 256)
        outp[(size_t)k * B + bb] = hist[k];
}

// ---- P2a: tot[pipe][k] = sum_b bh[pipe][k][b] ----
__global__ __launch_bounds__(256) void p2a_tot(const int* __restrict__ bh, int NBIN, int B,
                                               int* __restrict__ tot) {
    __shared__ int sc[256];
    int k = blockIdx.x % NBIN, pipe = blockIdx.x / NBIN;
    const int* row = bh + (size_t)pipe * NBIN * B + (size_t)k * B;
    int acc = 0;
    for (int b = threadIdx.x; b < B; b += 256) acc += row[b];
    sc[threadIdx.x] = acc;
    __syncthreads();
    for (int o = 128; o > 0; o >>= 1) {
        if (threadIdx.x < o) sc[threadIdx.x] += sc[threadIdx.x + o];
        __syncthreads();
    }
    if (threadIdx.x == 0) tot[pipe * NBIN + k] = sc[0];
}

// ---- P2c: block (pipe,k): base = prefix(tot) inline; write bstart; scan bh over B ----
__global__ __launch_bounds__(512) void p2c_cursor(const int* __restrict__ bh,
                                                  const int* __restrict__ tot,
                                                  int NBIN, int B, int E,
                                                  int* __restrict__ bstart,
                                                  int* __restrict__ curs) {
    __shared__ int sc[512];
    int k = blockIdx.x % NBIN, pipe = blockIdx.x / NBIN;
    int i = threadIdx.x;
    int pacc = 0;
    for (int kk = i; kk < k; kk += 512) pacc += tot[pipe * NBIN + kk];
    sc[i] = pacc;
    __syncthreads();
    for (int o = 256; o > 0; o >>= 1) {
        if (i < o) sc[i] += sc[i + o];
        __syncthreads();
    }
    int base = sc[0];
    __syncthreads();
    if (i == 0) {
        bstart[pipe * (NBIN + 1) + k] = base;
        if (k == 0) bstart[pipe * (NBIN + 1) + NBIN] = E;
    }
    const int* row = bh + (size_t)pipe * NBIN * B + (size_t)k * B;
    int v = (i < B) ? row[i] : 0;
    sc[i] = v;
    __syncthreads();
    for (int o = 1; o < 512; o <<= 1) {
        int t = (i >= o) ? sc[i - o] : 0;
        __syncthreads();
        sc[i] += t;
        __syncthreads();
    }
    if (i < B)
        curs[(size_t)pipe * B * NBIN + (size_t)i * NBIN + k] = base + sc[i] - v;
}

// ---- P3: scatter edges into bin-partitioned buffers (LDS cursors) ----
// pipe0 entry: src | (dst&255)<<17  (src < 2^17; dst low 8 bits for in-bin CSR)
// pipe1: low 8 bits of src as uint8 (all p4s needs)
__global__ __launch_bounds__(256) void p3_scatter(const int* __restrict__ src,
                                                  const int* __restrict__ dst, int E,
                                                  int NBIN, int B, const int* __restrict__ curs,
                                                  int* __restrict__ ebuf, uint8* __restrict__ sbuf) {
    __shared__ int cur[512];
    int b = blockIdx.x;
    int pipe = (b >= B) ? 1 : 0;
    int bb = pipe ? b - B : b;
    const int* crow = curs + (size_t)pipe * B * NBIN + (size_t)bb * NBIN;
    for (int i = threadIdx.x; i < NBIN; i += 256) cur[i] = crow[i];
    __syncthreads();
    int base = bb * PB_EDGES;
    if (!pipe) {
        for (int c = threadIdx.x; c < PB_EDGES / 4; c += 256) {
            int e = base + c * 4;
            if (e + 3 < E) {
                int4 s4 = *(const int4*)(src + e);
                int4 d4 = *(const int4*)(dst + e);
                int p;
                p = atomicAdd(&cur[d4.x >> 8], 1); ebuf[p] = s4.x | ((d4.x & 255) << 17);
                p = atomicAdd(&cur[d4.y >> 8], 1); ebuf[p] = s4.y | ((d4.y & 255) << 17);
                p = atomicAdd(&cur[d4.z >> 8], 1); ebuf[p] = s4.z | ((d4.z & 255) << 17);
                p = atomicAdd(&cur[d4.w >> 8], 1); ebuf[p] = s4.w | ((d4.w & 255) << 17);
            } else {
                for (int i = e; i < E && i < e + 4; i++) {
                    int s = src[i], d = dst[i];
                    int p = atomicAdd(&cur[d >> 8], 1);
                    ebuf[p] = s | ((d & 255) << 17);
                }
            }
        }
    } else {
        for (int c = threadIdx.x; c < PB_EDGES / 4; c += 256) {
            int e = base + c * 4;
            if (e + 3 < E) {
                int4 s4 = *(const int4*)(src + e);
                int p;
                p = atomicAdd(&cur[s4.x >> 8], 1); sbuf[p] = (uint8)(s4.x & 255);
                p = atomicAdd(&cur[s4.y >> 8], 1); sbuf[p] = (uint8)(s4.y & 255);
                p = atomicAdd(&cur[s4.z >> 8], 1); sbuf[p] = (uint8)(s4.z & 255);
                p = atomicAdd(&cur[s4.w >> 8], 1); sbuf[p] = (uint8)(s4.w & 255);
            } else {
                for (int i = e; i < E && i < e + 4; i++) {
                    int s = src[i];
                    int p = atomicAdd(&cur[s >> 8], 1);
                    sbuf[p] = (uint8)(s & 255);
                }
            }
        }
    }
}

// ---- P4 (fused): k<NBIN: per-bin CSR + nrm_in; k>=NBIN: outdeg hist -> nrm_out ----
__global__ __launch_bounds__(256) void p4_comb(const int* __restrict__ ebuf,
                                               const uint8* __restrict__ sbuf,
                                               const int* __restrict__ bstart,
                                               int NBIN, int N, int E,
                                               int* __restrict__ coff,
                                               int* __restrict__ adj,
                                               float* __restrict__ nrm_in,
                                               float* __restrict__ nrm_out) {
    __shared__ int hist[256];
    __shared__ int sc[256];
    __shared__ int cur[256];
    __shared__ int lsrc[8192];
    int kb = blockIdx.x;
    int tid = threadIdx.x;
    if (kb >= NBIN) {
        int k = kb - NBIN;
        const int* bstartS = bstart + (NBIN + 1);
        int s0 = bstartS[k], s1 = bstartS[k + 1];
        hist[tid] = 0;
        __syncthreads();
        for (int i = s0 + tid; i < s1; i += 256) atomicAdd(&hist[sbuf[i]], 1);
        __syncthreads();
        int node = k * W_BIN + tid;
        if (node < N) nrm_out[node] = rsqrtf(fmaxf((float)hist[tid], 1.0f));
        return;
    }
    int k = kb;
    int s0 = bstart[k], s1 = bstart[k + 1];
    int M = s1 - s0;
    hist[tid] = 0;
    __syncthreads();
    for (int i = tid; i < M; i += 256) {
        int e = ebuf[s0 + i];
        atomicAdd(&hist[(e >> 17) & 255], 1);
    }
    __syncthreads();
    sc[tid] = hist[tid];
    __syncthreads();
    for (int o = 1; o < 256; o <<= 1) {
        int v = (tid >= o) ? sc[tid - o] : 0;
        __syncthreads();
        sc[tid] += v;
        __syncthreads();
    }
    {
        int node = k * W_BIN + tid;
        if (node < N) {
            coff[node] = s0 + sc[tid] - hist[tid];
            nrm_in[node] = rsqrtf(fmaxf((float)hist[tid], 1.0f));
        }
        cur[tid] = sc[tid] - hist[tid];
    }
    if (k == NBIN - 1 && tid == 0) coff[N] = E;
    __syncthreads();
    if (M <= 8192) {
        for (int i = tid; i < M; i += 256) {
            int e = ebuf[s0 + i];
            int p = atomicAdd(&cur[(e >> 17) & 255], 1);
            lsrc[p] = e & 0x1FFFF;
        }
        __syncthreads();
        for (int i = tid; i < M; i += 256) adj[s0 + i] = lsrc[i];
    } else {
        for (int i = tid; i < M; i += 256) {
            int e = ebuf[s0 + i];
            int p = atomicAdd(&cur[(e >> 17) & 255], 1);
            adj[s0 + p] = e & 0x1FFFF;
        }
    }
}

// ---- xsb[n] = bf16(h[n] * nrm_out[n]) : 16 lanes/node, 8 elems/lane ----
__global__ void scale_kernel(const float* __restrict__ h, const float* __restrict__ nrm_out,
                             uint32* __restrict__ xsb, int N) {
    int t = blockIdx.x * blockDim.x + threadIdx.x;
    int node = t >> 4, q = t & 15;
    if (node >= N) return;
    float ns = nrm_out[node];
    const float4* hv = (const float4*)(h + (size_t)node * 128 + q * 8);
    float4 a = hv[0], b = hv[1];
    a.x *= ns; a.y *= ns; a.z *= ns; a.w *= ns;
    b.x *= ns; b.y *= ns; b.z *= ns; b.w *= ns;
    uint4 o;
    o.x = pack2(a.x, a.y); o.y = pack2(a.z, a.w);
    o.z = pack2(b.x, b.y); o.w = pack2(b.z, b.w);
    ((uint4*)xsb)[(size_t)node * 16 + q] = o;
}

__device__ __forceinline__ void acc8(float* acc, uint4 u) {
    acc[0] += bflo(u.x); acc[1] += bfhi(u.x); acc[2] += bflo(u.y); acc[3] += bfhi(u.y);
    acc[4] += bflo(u.z); acc[5] += bfhi(u.z); acc[6] += bflo(u.w); acc[7] += bfhi(u.w);
}

// ---- aggregation: 16 lanes/node, row-major 256B rows, unroll-4 (R8 optimum) ----
__global__ void agg_kernel(const uint32* __restrict__ xsb, const int* __restrict__ adj,
                           const int* __restrict__ coff, uint32* __restrict__ aggb, int N) {
    int t = blockIdx.x * blockDim.x + threadIdx.x;
    int node = t >> 4;
    int q = t & 15;
    if (node >= N) return;
    int jb = coff[node], je = coff[node + 1];
    float acc[8];
#pragma unroll
    for (int i = 0; i < 8; i++) acc[i] = 0.f;
    const uint4* rows = (const uint4*)xsb;
    int j = jb;
    for (; j + 3 < je; j += 4) {
        int s0 = adj[j], s1 = adj[j + 1], s2 = adj[j + 2], s3 = adj[j + 3];
        uint4 u0 = rows[(size_t)s0 * 16 + q];
        uint4 u1 = rows[(size_t)s1 * 16 + q];
        uint4 u2 = rows[(size_t)s2 * 16 + q];
        uint4 u3 = rows[(size_t)s3 * 16 + q];
        acc8(acc, u0); acc8(acc, u1); acc8(acc, u2); acc8(acc, u3);
    }
    for (; j < je; j++) {
        uint4 u = rows[(size_t)adj[j] * 16 + q];
        acc8(acc, u);
    }
    uint4 o;
    o.x = pack2(acc[0], acc[1]); o.y = pack2(acc[2], acc[3]);
    o.z = pack2(acc[4], acc[5]); o.w = pack2(acc[6], acc[7]);
    ((uint4*)aggb)[(size_t)node * 16 + q] = o;
}

// ---- MFMA GEMM: 4 waves x 32 rows = 128 rows/block; B-frag shared by 2 row-tiles ----
__global__ __launch_bounds__(256) void gemm_mfma(const unsigned short* __restrict__ A,
                                                 const unsigned short* __restrict__ Wtg,
                                                 const float* __restrict__ bias,
                                                 const float* __restrict__ rowscale,
                                                 const float* __restrict__ postscale,
                                                 unsigned short* __restrict__ out,
                                                 int N, int do_relu) {
    __shared__ unsigned short Wl[128 * 136];
    for (int i = threadIdx.x; i < 2048; i += 256) {
        uint4 v = ((const uint4*)Wtg)[i];
        *(uint4*)&Wl[(i >> 4) * 136 + (i & 15) * 8] = v;
    }
    __syncthreads();

    int lane = threadIdx.x & 63;
    int wv = threadIdx.x >> 6;
    int col_l = lane & 15;
    int quad = lane >> 4;
    int r0w = blockIdx.x * 128 + wv * 32;
    if (r0w >= N) return;

    int arow0 = r0w + col_l;        if (arow0 >= N) arow0 = N - 1;
    int arow1 = r0w + 16 + col_l;   if (arow1 >= N) arow1 = N - 1;
    const unsigned short* Ar0 = A + (size_t)arow0 * 128;
    const unsigned short* Ar1 = A + (size_t)arow1 * 128;

    f32x4 acc[2][8];
#pragma unroll
    for (int rt = 0; rt < 2; rt++)
#pragma unroll
        for (int t = 0; t < 8; t++) {
            acc[rt][t][0] = 0.f; acc[rt][t][1] = 0.f;
            acc[rt][t][2] = 0.f; acc[rt][t][3] = 0.f;
        }

#pragma unroll
    for (int kk = 0; kk < 4; kk++) {
        bf16x8 a0 = *(const bf16x8*)(Ar0 + kk * 32 + quad * 8);
        bf16x8 a1 = *(const bf16x8*)(Ar1 + kk * 32 + quad * 8);
        const unsigned short* wb = &Wl[(size_t)col_l * 136 + kk * 32 + quad * 8];
#pragma unroll
        for (int t = 0; t < 8; t++) {
            bf16x8 b = *(const bf16x8*)(wb + (size_t)t * 16 * 136);
            acc[0][t] = __builtin_amdgcn_mfma_f32_16x16x32_bf16(a0, b, acc[0][t], 0, 0, 0);
            acc[1][t] = __builtin_amdgcn_mfma_f32_16x16x32_bf16(a1, b, acc[1][t], 0, 0, 0);
        }
    }

#pragma unroll
    for (int rt = 0; rt < 2; rt++) {
        int rbase = r0w + rt * 16;
        float s[4], p[4];
#pragma unroll
        for (int j = 0; j < 4; j++) {
            int rw = rbase + quad * 4 + j;
            bool ok = rw < N;
            s[j] = ok ? rowscale[ok ? rw : 0] : 0.f;
            p[j] = (postscale != nullptr && ok) ? postscale[rw] : 1.f;
        }
#pragma unroll
        for (int t = 0; t < 8; t++) {
            int c = t * 16 + col_l;
            float bia = bias[c];
#pragma unroll
            for (int j = 0; j < 4; j++) {
                int rw = rbase + quad * 4 + j;
                if (rw >= N) continue;
                float v = fmaf(s[j], acc[rt][t][j], bia);
                if (do_relu) v = fmaxf(v, 0.f);
                v *= p[j];
                out[(size_t)rw * 128 + c] = (unsigned short)f2bf_bits(v);
            }
        }
    }
}

// ---- fused per-graph mean + classifier head ----
__global__ __launch_bounds__(1024) void mean_final(const uint32* __restrict__ x2b,
                                                   const int* __restrict__ goffs,
                                                   const float* __restrict__ perm,
                                                   const float* __restrict__ Wc,
                                                   const float* __restrict__ bc,
                                                   float* __restrict__ out) {
    __shared__ float red[16][128];
    __shared__ float hrow[128];
    int g = blockIdx.x;
    int cp = threadIdx.x & 63;
    int j = threadIdx.x >> 6;  // 0..15
    int s = goffs[g], e = goffs[g + 1];
    float a0 = 0.f, a1 = 0.f;
    for (int r = s + j; r < e; r += 16) {
        uint32 u = x2b[(size_t)r * 64 + cp];
        a0 += bflo(u); a1 += bfhi(u);
    }
    red[j][cp * 2] = a0;
    red[j][cp * 2 + 1] = a1;
    __syncthreads();
    if (j == 0) {
        float t0 = 0.f, t1 = 0.f;
#pragma unroll
        for (int jj = 0; jj < 16; jj++) { t0 += red[jj][cp * 2]; t1 += red[jj][cp * 2 + 1]; }
        float cnt = fmaxf((float)(e - s), 1.0f);
        hrow[cp * 2] = t0 / cnt;
        hrow[cp * 2 + 1] = t1 / cnt;
    }
    __syncthreads();
    if (threadIdx.x < 10) {
        int c = threadIdx.x;
        float acc = bc[c];
#pragma unroll 8
        for (int k = 0; k < 128; k++) acc = fmaf(hrow[k], Wc[k * 10 + c], acc);
        const float* prow = perm + g * 64;
#pragma unroll 8
        for (int p = 0; p < 64; p++) acc = fmaf(prow[p], Wc[(128 + p) * 10 + c], acc);
        out[g * 10 + c] = acc;
    }
}

extern "C" void kernel_launch(void* const* d_in, const int* in_sizes, int n_in,
                              void* d_out, int out_size, void* d_ws, size_t ws_size,
                              hipStream_t stream) {
    const float* h    = (const float*)d_in[0];
    const float* perm = (const float*)d_in[1];
    const float* W1   = (const float*)d_in[2];
    const float* b1   = (const float*)d_in[3];
    const float* W2   = (const float*)d_in[4];
    const float* b2   = (const float*)d_in[5];
    const float* Wc   = (const float*)d_in[6];
    const float* bc   = (const float*)d_in[7];
    const int* src    = (const int*)d_in[8];
    const int* dst    = (const int*)d_in[9];
    const int* gids   = (const int*)d_in[10];
    float* out = (float*)d_out;

    const int N = in_sizes[0] / 128;
    const int E = in_sizes[8];
    const int G = NUM_G, H = 128;
    const int B = (E + PB_EDGES - 1) / PB_EDGES;
    const int NBIN = (N + W_BIN - 1) / W_BIN;
    const int GB = (N + 1 + 255) / 256;   // goffs blocks

    char* w = (char*)d_ws;
    size_t off = 0;
    auto alloc = [&](size_t bytes) -> void* {
        void* p = w + off;
        off = (off + bytes + 255) & ~(size_t)255;
        return p;
    };
    uint32* xsb   = (uint32*)alloc((size_t)N * H * 2);  // bf16 scaled in; later x2 out
    uint32* aggb  = (uint32*)alloc((size_t)N * H * 2);  // bf16 agg out (both layers)
    uint32* x1b   = (uint32*)alloc((size_t)N * H * 2);  // bf16 layer-1 out
    unsigned short* Wt1 = (unsigned short*)alloc(16384 * 2);
    unsigned short* Wt2 = (unsigned short*)alloc(16384 * 2);
    int*    adj     = (int*)alloc((size_t)E * 4);
    int*    coff    = (int*)alloc((size_t)(N + 1) * 4);
    float*  nrm_out = (float*)alloc((size_t)N * 4);
    float*  nrm_in  = (float*)alloc((size_t)N * 4);
    int*    goffs   = (int*)alloc((size_t)(G + 1) * 4);

    // Build temporaries alias aggb (dead until agg_kernel writes it).
    char* tmp = (char*)aggb;
    size_t toff = 0;
    auto talloc = [&](size_t bytes) -> void* {
        void* p = tmp + toff;
        toff = (toff + bytes + 255) & ~(size_t)255;
        return p;
    };
    int*   ebuf   = (int*)talloc((size_t)E * 4);   // packed src | dstlow<<17
    uint8* sbuf   = (uint8*)talloc((size_t)E);     // low 8 bits of src
    int*   bh     = (int*)talloc((size_t)2 * B * NBIN * 4);
    int*   curs   = (int*)talloc((size_t)2 * B * NBIN * 4);
    int*   tot    = (int*)talloc((size_t)2 * NBIN * 4);
    int*   bstart = (int*)talloc((size_t)2 * (NBIN + 1) * 4);

    // ---- atomic-free graph build (+ goffs + Wt piggybacked on p1) ----
    p1_hist<<<2 * B + GB + 128, 256, 0, stream>>>(src, dst, E, NBIN, B, GB, N,
                                                  gids, W1, W2, bh, goffs, Wt1, Wt2);
    p2a_tot<<<2 * NBIN, 256, 0, stream>>>(bh, NBIN, B, tot);
    p2c_cursor<<<2 * NBIN, 512, 0, stream>>>(bh, tot, NBIN, B, E, bstart, curs);
    p3_scatter<<<2 * B, 256, 0, stream>>>(src, dst, E, NBIN, B, curs, ebuf, sbuf);
    p4_comb<<<2 * NBIN, 256, 0, stream>>>(ebuf, sbuf, bstart, NBIN, N, E,
                                          coff, adj, nrm_in, nrm_out);

    // layer 1
    scale_kernel<<<(N * 16 + 255) / 256, 256, 0, stream>>>(h, nrm_out, xsb, N);
    agg_kernel<<<(N * 16 + 255) / 256, 256, 0, stream>>>(xsb, adj, coff, aggb, N);
    gemm_mfma<<<(N + 127) / 128, 256, 0, stream>>>((const unsigned short*)aggb, Wt1, b1,
                                                   nrm_in, nrm_out,
                                                   (unsigned short*)x1b, N, 1);

    // layer 2 (output bf16 into xsb, dead after agg1)
    agg_kernel<<<(N * 16 + 255) / 256, 256, 0, stream>>>(x1b, adj, coff, aggb, N);
    gemm_mfma<<<(N + 127) / 128, 256, 0, stream>>>((const unsigned short*)aggb, Wt2, b2,
                                                   nrm_in, nullptr,
                                                   (unsigned short*)xsb, N, 0);

    // fused readout
    mean_final<<<G, 1024, 0, stream>>>(xsb, goffs, perm, Wc, bc, out);
}